// Round 7
// baseline (703106.299 us; speedup 1.0000x reference)
//
#include <hip/hip_runtime.h>
#include <math.h>

#define T_DIM 512
#define B_DIM 64
#define I_DIM 1024
#define H_DIM 1024
#define CH    64          // k-chunk
#define NCH   16          // 1024 / CH
#define QF    16          // float4 groups per chunk (CH/4)

// d_out layout (flat f32): ys [T][B][2H], hT_f [B][H], cT_f, hT_b, cT_b
#define OUT_HTF (T_DIM * B_DIM * 2 * H_DIM)
#define OUT_CTF (OUT_HTF + B_DIM * H_DIM)
#define OUT_HTB (OUT_CTF + B_DIM * H_DIM)
#define OUT_CTB (OUT_HTB + B_DIM * H_DIM)

__device__ __forceinline__ float sigmoidf_(float v) {
    return 1.0f / (1.0f + expf(-v));
}

// One launch per step s (plus prologue s=-1). Grid 512 x 256 threads.
//   bid < 256 : h-role — gates = gx[s&1] + h_{s-1} @ W_hh^T ; cell update
//   bid >= 256: x-role — gx[(s+1)&1] = x_{t(s+1)} @ W_ih^T + bias
// Role id rid: dir = rid>>7, us = rid&127 -> block owns 32 gate-cols
// ({i,f,g,o} x units u0..u0+7), 64 batch rows, K = 1024.
// Wave = gate (W addresses wave-uniform -> one broadcast transaction per
// load); lane = batch row; thread tile = 1m x 8n.
// A staged in LDS [q][m] float4 layout, +1 f4 row pad (bank-optimal both
// sides); 3-deep software pipeline on both the LDS a-reads and the global
// W-broadcast stream. One barrier per k-chunk.
__global__ __launch_bounds__(256, 2) void lstm_step(
    const float* __restrict__ x,
    const float* __restrict__ h0f, const float* __restrict__ c0f,
    const float* __restrict__ h0b, const float* __restrict__ c0b,
    const float* __restrict__ wihf, const float* __restrict__ whhf,
    const float* __restrict__ bihf, const float* __restrict__ bhhf,
    const float* __restrict__ wihb, const float* __restrict__ whhb,
    const float* __restrict__ bihb, const float* __restrict__ bhhb,
    float* __restrict__ out, float* __restrict__ gx, int s)
{
    __shared__ float4 stage[2][QF * 65];   // 2 x 16.6 KB, row-padded
    __shared__ float  Lg[32 * 65];         // gate exchange, padded

    const int tid  = threadIdx.x;
    const int bid  = blockIdx.x;
    const bool hrole = (bid < 256);
    const int rid  = bid & 255;
    const int dir  = rid >> 7;
    const int u0   = (rid & 127) * 8;
    const int us   = rid & 127;
    const int g    = tid >> 6;             // wave = gate 0..3
    const int lane = tid & 63;             // batch row m

    // ---- role setup ----
    const float* A;  int sA;  const float* W;  int t;
    if (hrole) {
        if (s < 0) return;
        t = dir ? (T_DIM - 1 - s) : s;
        if (s == 0) { A = dir ? h0b : h0f; sA = H_DIM; }
        else {
            const int tp = dir ? (t + 1) : (t - 1);
            A = out + (size_t)tp * B_DIM * 2 * H_DIM + dir * H_DIM;
            sA = 2 * H_DIM;
        }
        W = dir ? whhb : whhf;
    } else {
        const int sx = s + 1;
        if (sx >= T_DIM) return;
        t = dir ? (T_DIM - 1 - sx) : sx;
        A = x + (size_t)t * B_DIM * I_DIM;
        sA = I_DIM;
        W = dir ? wihb : wihf;
    }

    const int j0 = g * H_DIM + u0;         // this wave's first gate-col / W row
    const float4* W4 = reinterpret_cast<const float4*>(W);

    float acc[8];
    if (hrole) {
#pragma unroll
        for (int ci = 0; ci < 8; ++ci) acc[ci] = 0.f;
    } else {
        const float* bi = dir ? bihb : bihf;
        const float* bh = dir ? bhhb : bhhf;
#pragma unroll
        for (int ci = 0; ci < 8; ++ci) acc[ci] = bi[j0 + ci] + bh[j0 + ci];
    }

    // ---- staging: global A chunk -> regs -> LDS [q][m] (padded 65) ----
    float4 sreg[4];
    auto issue = [&](int kc) {
#pragma unroll
        for (int p = 0; p < 4; ++p) {
            const int e = p * 256 + tid;   // 0..1023
            const int m = e >> 4, q = e & 15;
            sreg[p] = *reinterpret_cast<const float4*>(
                A + (size_t)m * sA + kc * CH + q * 4);
        }
    };
    auto commit = [&](int buf) {
#pragma unroll
        for (int p = 0; p < 4; ++p) {
            const int e = p * 256 + tid;
            const int m = e >> 4, q = e & 15;
            stage[buf][q * 65 + m] = sreg[p];
        }
    };

    issue(0);
    commit(0);
    __syncthreads();

    for (int kc = 0; kc < NCH; ++kc) {
        if (kc + 1 < NCH) issue(kc + 1);
        const int buf = kc & 1;
        const float4* wrow = W4 + (size_t)j0 * 256 + kc * QF;

        // 3-deep pipeline: a from LDS, w broadcast from global
        float4 a[3];
        float4 w[3][8];
#pragma unroll
        for (int pq = 0; pq < 3; ++pq) {
            a[pq] = stage[buf][pq * 65 + lane];
#pragma unroll
            for (int ci = 0; ci < 8; ++ci)
                w[pq][ci] = wrow[(size_t)ci * 256 + pq];
        }
#pragma unroll
        for (int q = 0; q < QF; ++q) {
            const int cur = q % 3;
            const float4 av = a[cur];
            float4 wv[8];
#pragma unroll
            for (int ci = 0; ci < 8; ++ci) wv[ci] = w[cur][ci];
            if (q + 3 < QF) {
                a[cur] = stage[buf][(q + 3) * 65 + lane];
#pragma unroll
                for (int ci = 0; ci < 8; ++ci)
                    w[cur][ci] = wrow[(size_t)ci * 256 + (q + 3)];
            }
#pragma unroll
            for (int ci = 0; ci < 8; ++ci)
                acc[ci] = fmaf(av.x, wv[ci].x, fmaf(av.y, wv[ci].y,
                          fmaf(av.z, wv[ci].z, fmaf(av.w, wv[ci].w,
                               acc[ci]))));
        }
        if (kc + 1 < NCH) {
            commit((kc + 1) & 1);
            __syncthreads();
        }
    }

    if (!hrole) {
        // write gx ring slot (s+1)&1, block-contiguous [g][m][8] layout
        const int sx = s + 1;
        float4* gw = reinterpret_cast<float4*>(gx)
            + (((size_t)(sx & 1) * 2 + dir) * 128 + us) * 512
            + (g * 64 + lane) * 2;
        gw[0] = make_float4(acc[0], acc[1], acc[2], acc[3]);
        gw[1] = make_float4(acc[4], acc[5], acc[6], acc[7]);
        return;
    }

    // ---- h-role epilogue: + gx, gate exchange, cell update ----
    {
        const float4* gb = reinterpret_cast<const float4*>(gx)
            + (((size_t)(s & 1) * 2 + dir) * 128 + us) * 512
            + (g * 64 + lane) * 2;
        const float4 g0 = gb[0], g1 = gb[1];
        acc[0] += g0.x; acc[1] += g0.y; acc[2] += g0.z; acc[3] += g0.w;
        acc[4] += g1.x; acc[5] += g1.y; acc[6] += g1.z; acc[7] += g1.w;
    }
    __syncthreads();                       // GEMM LDS reuse done
#pragma unroll
    for (int ci = 0; ci < 8; ++ci)
        Lg[(g * 8 + ci) * 65 + lane] = acc[ci];
    __syncthreads();

    const int u  = tid & 7;
    const int mr = tid >> 3;               // 0..31
    float* cslot = out + (dir ? OUT_CTB : OUT_CTF);
    float* hslot = out + (dir ? OUT_HTB : OUT_HTF);
    const float* cinit = dir ? c0b : c0f;
#pragma unroll
    for (int hf = 0; hf < 2; ++hf) {
        const int m = mr + hf * 32;
        const float ig = Lg[(0  + u) * 65 + m];
        const float fg = Lg[(8  + u) * 65 + m];
        const float gg = Lg[(16 + u) * 65 + m];
        const float og = Lg[(24 + u) * 65 + m];
        const float cp = (s == 0) ? cinit[(size_t)m * H_DIM + u0 + u]
                                  : cslot[(size_t)m * H_DIM + u0 + u];
        const float cn = sigmoidf_(fg) * cp + sigmoidf_(ig) * tanhf(gg);
        const float hv = sigmoidf_(og) * tanhf(cn);
        cslot[(size_t)m * H_DIM + u0 + u] = cn;
        out[(size_t)t * B_DIM * 2 * H_DIM + (size_t)m * 2 * H_DIM
            + dir * H_DIM + u0 + u] = hv;
        if (s == T_DIM - 1) hslot[(size_t)m * H_DIM + u0 + u] = hv;
    }
}

extern "C" void kernel_launch(void* const* d_in, const int* in_sizes, int n_in,
                              void* d_out, int out_size, void* d_ws, size_t ws_size,
                              hipStream_t stream)
{
    const float* x    = (const float*)d_in[0];
    const float* h0f  = (const float*)d_in[1];
    const float* c0f  = (const float*)d_in[2];
    const float* h0b  = (const float*)d_in[3];
    const float* c0b  = (const float*)d_in[4];
    const float* wihf = (const float*)d_in[5];
    const float* whhf = (const float*)d_in[6];
    const float* bihf = (const float*)d_in[7];
    const float* bhhf = (const float*)d_in[8];
    const float* wihb = (const float*)d_in[9];
    const float* whhb = (const float*)d_in[10];
    const float* bihb = (const float*)d_in[11];
    const float* bhhb = (const float*)d_in[12];
    float* out = (float*)d_out;
    float* gx  = (float*)d_ws;             // 4 MB ring (2 slots), ws >= 4.2 MB proven

    for (int s = -1; s < T_DIM; ++s) {
        lstm_step<<<dim3(512), dim3(256), 0, stream>>>(
            x, h0f, c0f, h0b, c0b,
            wihf, whhf, bihf, bhhf,
            wihb, whhb, bihb, bhhb,
            out, gx, s);
    }
}

// Round 8
// 105334.900 us; speedup vs baseline: 6.6750x; 6.6750x over previous
//
#include <hip/hip_runtime.h>
#include <math.h>

#define T_DIM 512
#define B_DIM 64
#define I_DIM 1024
#define H_DIM 1024

// d_out layout (flat f32): ys [T][B][2H], hT_f [B][H], cT_f, hT_b, cT_b
#define OUT_HTF (T_DIM * B_DIM * 2 * H_DIM)
#define OUT_CTF (OUT_HTF + B_DIM * H_DIM)
#define OUT_HTB (OUT_CTF + B_DIM * H_DIM)
#define OUT_CTB (OUT_HTB + B_DIM * H_DIM)

__device__ __forceinline__ float sigmoidf_(float v) {
    return 1.0f / (1.0f + expf(-v));
}

__device__ __forceinline__ float dpp_xor1(float v) {
    // quad_perm [1,0,3,2]: swap adjacent lanes within each quad (ks ^= 1)
    int r = __builtin_amdgcn_update_dpp(0, __float_as_int(v), 0xB1, 0xF, 0xF, true);
    return __int_as_float(r);
}

// ---------------------------------------------------------------------------
// Persistent bidirectional LSTM with W resident in VGPRs.
// Grid: 256 blocks x 512 threads, 1 block/CU (151 KB LDS forces it).
//   bid < 128 : h-role (dir = rid>>6, ub = rid&63): gates = gx + h@W_hh^T, cell
//   bid >= 128: x-role: gx ring slot = x_t@W_ih^T + bias, one step ahead
// Each CU owns 64 gate-rows: row r = gate*16 + unit (units ub*16..+15).
// Waves: wid = (wk<<2)|wr : wk = k-half (512), wr = gate. Lane: rl = row
// within gate (0..15), ks = k-quarter (0..3).
// W per lane: row (wr*16+rl), k = wk*512 + c*64 + ks*16 + [0,16) for c=0..7
//   -> float4 wv[32], loaded ONCE. Zero W memory traffic during recurrence.
// A staged per 64-k chunk (both wk windows): LDS [64 m][128], double-buffered.
// acc[8] per m-tile; DPP quad-reduce over ks-pairs; partials in LDS pg[wk][kp];
// combined once per step (+bias / +gx), then cell update (c-state in regs).
// Grid barrier per round (proven r6 two-level atomic).
// ---------------------------------------------------------------------------
__global__ __launch_bounds__(512, 2) void lstm_wreg(
    const float* __restrict__ x,
    const float* __restrict__ h0f, const float* __restrict__ c0f,
    const float* __restrict__ h0b, const float* __restrict__ c0b,
    const float* __restrict__ wihf, const float* __restrict__ whhf,
    const float* __restrict__ bihf, const float* __restrict__ bhhf,
    const float* __restrict__ wihb, const float* __restrict__ whhb,
    const float* __restrict__ bihb, const float* __restrict__ bhhb,
    float* __restrict__ out, float* __restrict__ gx, int* __restrict__ bar)
{
    __shared__ float stg[2][64 * 128];     // 64 KB  A-chunk double buffer
    __shared__ float pg[2][2][64 * 68];    // 69.6 KB partial gates [wk][kp]
    __shared__ float gatesL[64 * 68];      // 17.4 KB combined gates (h-role)

    const int tid = threadIdx.x;
    const int bid = blockIdx.x;
    const bool hrole = (bid < 128);
    const int rid = bid & 127;
    const int dir = rid >> 6;
    const int ub  = rid & 63;              // unit-block: units ub*16..+15
    const int wid = tid >> 6;
    const int wk  = wid >> 2;              // k-half 0..1
    const int wr  = wid & 3;               // gate 0..3
    const int lane = tid & 63;
    const int rl  = lane >> 2;             // row-in-gate 0..15
    const int ks  = lane & 3;              // k-quarter 0..3
    const int ke  = ks & 1;
    const int kp  = ks >> 1;
    const int rloc = wr * 16 + rl;         // local row 0..63
    const int grow = wr * H_DIM + ub * 16 + rl;  // global gate-row

    // ---- load W slice into registers (once) ----
    const float* W = hrole ? (dir ? whhb : whhf) : (dir ? wihb : wihf);
    float4 wv[32];
#pragma unroll
    for (int c = 0; c < 8; ++c)
#pragma unroll
        for (int f = 0; f < 4; ++f)
            wv[c * 4 + f] = *reinterpret_cast<const float4*>(
                W + (size_t)grow * 1024 + wk * 512 + c * 64 + ks * 16 + f * 4);

    // combine-phase mapping: thread t -> row rC, cols m0..m0+7
    const int rC = tid >> 3;
    const int m0 = (tid & 7) * 8;
    float biasC = 0.f;
    if (!hrole) {
        const int growC = (rC >> 4) * H_DIM + ub * 16 + (rC & 15);
        const float* bi = dir ? bihb : bihf;
        const float* bh = dir ? bhhb : bhhf;
        biasC = bi[growC] + bh[growC];
    }

    // h-role: persistent c-state, 2 cells/thread: cell = 2*tid+e -> (m, ul)
    float creg[2] = {0.f, 0.f};
    if (hrole) {
        const float* ci = dir ? c0b : c0f;
#pragma unroll
        for (int e = 0; e < 2; ++e) {
            const int cell = 2 * tid + e;
            creg[e] = ci[(size_t)(cell >> 4) * H_DIM + ub * 16 + (cell & 15)];
        }
    }

    float4 sreg[4];
    const float* A = nullptr;
    int sA = 0;

    auto stage_issue = [&](int c) {
#pragma unroll
        for (int p = 0; p < 4; ++p) {
            const int e = p * 512 + tid;   // f4-slot 0..2047
            const int m = e >> 5;
            const int rest = e & 31;
            const int wkk = rest >> 4, fg = rest & 15;
            sreg[p] = *reinterpret_cast<const float4*>(
                A + (size_t)m * sA + wkk * 512 + c * 64 + fg * 4);
        }
    };
    auto stage_commit = [&](int buf) {
#pragma unroll
        for (int p = 0; p < 4; ++p) {
            const int e = p * 512 + tid;
            const int m = e >> 5;
            const int rest = e & 31;
            const int wkk = rest >> 4, fg = rest & 15;
            *reinterpret_cast<float4*>(
                &stg[buf][m * 128 + wkk * 64 + fg * 4]) = sreg[p];
        }
    };

    // ================= main rounds =================
    for (int r = 0; r <= T_DIM; ++r) {
        const int s = hrole ? (r - 1) : r;
        const bool active = (s >= 0 && s < T_DIM);

        if (active) {
            const int tt = dir ? (T_DIM - 1 - s) : s;
            if (hrole) {
                if (s == 0) { A = dir ? h0b : h0f; sA = H_DIM; }
                else {
                    const int tp = dir ? (tt + 1) : (tt - 1);
                    A = out + (size_t)tp * B_DIM * 2 * H_DIM + dir * H_DIM;
                    sA = 2 * H_DIM;
                }
            } else {
                A = x + (size_t)tt * B_DIM * I_DIM;
                sA = I_DIM;
            }

            stage_issue(0);
            stage_commit(0);
            __syncthreads();

            float* pgbase = &pg[wk][kp][0];
#pragma unroll
            for (int c = 0; c < 8; ++c) {
                if (c < 7) stage_issue(c + 1);
                const float* sb = &stg[c & 1][wk * 64 + ks * 16];
#pragma unroll 1
                for (int mt = 0; mt < 8; ++mt) {
                    float a0 = 0.f, a1 = 0.f, a2 = 0.f, a3 = 0.f;
                    float a4 = 0.f, a5 = 0.f, a6 = 0.f, a7 = 0.f;
                    const float* hp = sb + mt * 8 * 128;
#pragma unroll
                    for (int f = 0; f < 4; ++f) {
                        const float4 w = wv[c * 4 + f];
#define FMA_ROW(ACC, MM)                                                   \
                        {                                                  \
                            const float4 av = *reinterpret_cast<const float4*>( \
                                hp + (MM) * 128 + f * 4);                  \
                            ACC = fmaf(av.x, w.x, fmaf(av.y, w.y,          \
                                  fmaf(av.z, w.z, fmaf(av.w, w.w, ACC)))); \
                        }
                        FMA_ROW(a0, 0) FMA_ROW(a1, 1) FMA_ROW(a2, 2) FMA_ROW(a3, 3)
                        FMA_ROW(a4, 4) FMA_ROW(a5, 5) FMA_ROW(a6, 6) FMA_ROW(a7, 7)
#undef FMA_ROW
                    }
                    // reduce over ks-pairs (DPP, VALU pipe)
                    a0 += dpp_xor1(a0); a1 += dpp_xor1(a1);
                    a2 += dpp_xor1(a2); a3 += dpp_xor1(a3);
                    a4 += dpp_xor1(a4); a5 += dpp_xor1(a5);
                    a6 += dpp_xor1(a6); a7 += dpp_xor1(a7);
                    // lane ks writes m-half ke: cols mt*8 + ke*4 .. +3
                    const float v0 = ke ? a4 : a0;
                    const float v1 = ke ? a5 : a1;
                    const float v2 = ke ? a6 : a2;
                    const float v3 = ke ? a7 : a3;
                    float* pp = pgbase + rloc * 68 + mt * 8 + ke * 4;
                    if (c == 0) {
                        *reinterpret_cast<float4*>(pp) =
                            make_float4(v0, v1, v2, v3);
                    } else {
                        float4 o = *reinterpret_cast<const float4*>(pp);
                        o.x += v0; o.y += v1; o.z += v2; o.w += v3;
                        *reinterpret_cast<float4*>(pp) = o;
                    }
                }
                if (c < 7) {
                    stage_commit((c + 1) & 1);
                    __syncthreads();
                }
            }
            __syncthreads();   // all pg partials done

            // ---- combine: gates[rC][m0..+7] = sum of 4 pg planes ----
            float g8[8];
#pragma unroll
            for (int half = 0; half < 2; ++half) {
                const int o = rC * 68 + m0 + half * 4;
                float4 t0 = *reinterpret_cast<const float4*>(&pg[0][0][o]);
                const float4 t1 = *reinterpret_cast<const float4*>(&pg[0][1][o]);
                const float4 t2 = *reinterpret_cast<const float4*>(&pg[1][0][o]);
                const float4 t3 = *reinterpret_cast<const float4*>(&pg[1][1][o]);
                g8[half * 4 + 0] = t0.x + t1.x + t2.x + t3.x;
                g8[half * 4 + 1] = t0.y + t1.y + t2.y + t3.y;
                g8[half * 4 + 2] = t0.z + t1.z + t2.z + t3.z;
                g8[half * 4 + 3] = t0.w + t1.w + t2.w + t3.w;
            }

            if (!hrole) {
                // + bias, write gx ring slot s&1
                float* gw = gx + (size_t)(s & 1) * 524288 + dir * 262144
                            + ub * 4096 + rC * 64 + m0;
#pragma unroll
                for (int j = 0; j < 8; ++j) g8[j] += biasC;
                *reinterpret_cast<float4*>(gw) =
                    make_float4(g8[0], g8[1], g8[2], g8[3]);
                *reinterpret_cast<float4*>(gw + 4) =
                    make_float4(g8[4], g8[5], g8[6], g8[7]);
            } else {
                // + gx, stash combined gates, cell update
                const float* gr = gx + (size_t)(s & 1) * 524288 + dir * 262144
                                  + ub * 4096 + rC * 64 + m0;
                const float4 q0 = *reinterpret_cast<const float4*>(gr);
                const float4 q1 = *reinterpret_cast<const float4*>(gr + 4);
                g8[0] += q0.x; g8[1] += q0.y; g8[2] += q0.z; g8[3] += q0.w;
                g8[4] += q1.x; g8[5] += q1.y; g8[6] += q1.z; g8[7] += q1.w;
                float* gp = &gatesL[rC * 68 + m0];
                *reinterpret_cast<float4*>(gp) =
                    make_float4(g8[0], g8[1], g8[2], g8[3]);
                *reinterpret_cast<float4*>(gp + 4) =
                    make_float4(g8[4], g8[5], g8[6], g8[7]);
                __syncthreads();

                float* cslot = out + (dir ? OUT_CTB : OUT_CTF);
                float* hslot = out + (dir ? OUT_HTB : OUT_HTF);
#pragma unroll
                for (int e = 0; e < 2; ++e) {
                    const int cell = 2 * tid + e;
                    const int m = cell >> 4;
                    const int ul = cell & 15;
                    const float ig = gatesL[(0  + ul) * 68 + m +  0 * 68 * 16];
                    const float fg = gatesL[(16 + ul) * 68 + m];
                    const float gg = gatesL[(32 + ul) * 68 + m];
                    const float og = gatesL[(48 + ul) * 68 + m];
                    const float cn = sigmoidf_(fg) * creg[e]
                                   + sigmoidf_(ig) * tanhf(gg);
                    const float hv = sigmoidf_(og) * tanhf(cn);
                    creg[e] = cn;
                    out[(size_t)tt * B_DIM * 2 * H_DIM + (size_t)m * 2 * H_DIM
                        + dir * H_DIM + ub * 16 + ul] = hv;
                    if (s == T_DIM - 1) {
                        hslot[(size_t)m * H_DIM + ub * 16 + ul] = hv;
                        cslot[(size_t)m * H_DIM + ub * 16 + ul] = creg[e];
                    }
                }
            }
        }

        // ---- grid barrier, generation r+1 (none after final round) ----
        if (r < T_DIM) {
            __threadfence();
            __syncthreads();
            if (tid == 0) {
                const int grp = bid >> 5;
                __hip_atomic_fetch_add(&bar[grp], 1, __ATOMIC_RELEASE,
                                       __HIP_MEMORY_SCOPE_AGENT);
                if ((bid & 31) == 0) {
                    while (__hip_atomic_load(&bar[grp], __ATOMIC_ACQUIRE,
                                             __HIP_MEMORY_SCOPE_AGENT)
                           < 32 * (r + 1))
                        __builtin_amdgcn_s_sleep(2);
                    __hip_atomic_fetch_add(&bar[8], 1, __ATOMIC_RELEASE,
                                           __HIP_MEMORY_SCOPE_AGENT);
                }
                while (__hip_atomic_load(&bar[8], __ATOMIC_ACQUIRE,
                                         __HIP_MEMORY_SCOPE_AGENT)
                       < 8 * (r + 1))
                    __builtin_amdgcn_s_sleep(2);
            }
            __syncthreads();
            __threadfence();
        }
    }
}

extern "C" void kernel_launch(void* const* d_in, const int* in_sizes, int n_in,
                              void* d_out, int out_size, void* d_ws, size_t ws_size,
                              hipStream_t stream)
{
    const float* x    = (const float*)d_in[0];
    const float* h0f  = (const float*)d_in[1];
    const float* c0f  = (const float*)d_in[2];
    const float* h0b  = (const float*)d_in[3];
    const float* c0b  = (const float*)d_in[4];
    const float* wihf = (const float*)d_in[5];
    const float* whhf = (const float*)d_in[6];
    const float* bihf = (const float*)d_in[7];
    const float* bhhf = (const float*)d_in[8];
    const float* wihb = (const float*)d_in[9];
    const float* whhb = (const float*)d_in[10];
    const float* bihb = (const float*)d_in[11];
    const float* bhhb = (const float*)d_in[12];
    float* out = (float*)d_out;

    // ws: [0,256) barrier counters, [256, 256+4MB) gx ring (2 slots x 2MB)
    hipMemsetAsync(d_ws, 0, 256, stream);
    float* gx = (float*)((char*)d_ws + 256);
    lstm_wreg<<<dim3(256), dim3(512), 0, stream>>>(
        x, h0f, c0f, h0b, c0b,
        wihf, whhf, bihf, bhhf,
        wihb, whhb, bihb, bhhb,
        out, gx, (int*)d_ws);
}

// Round 9
// 56007.501 us; speedup vs baseline: 12.5538x; 1.8807x over previous
//
#include <hip/hip_runtime.h>
#include <math.h>

#define T_DIM 512
#define B_DIM 64
#define I_DIM 1024
#define H_DIM 1024

// d_out layout (flat f32): ys [T][B][2H], hT_f [B][H], cT_f, hT_b, cT_b
#define OUT_HTF (T_DIM * B_DIM * 2 * H_DIM)
#define OUT_CTF (OUT_HTF + B_DIM * H_DIM)
#define OUT_HTB (OUT_CTF + B_DIM * H_DIM)
#define OUT_CTB (OUT_HTB + B_DIM * H_DIM)

typedef __attribute__((ext_vector_type(8))) short bf16x8;
typedef __attribute__((ext_vector_type(4))) float f32x4;

__device__ __forceinline__ float sigmoidf_(float v) {
    return 1.0f / (1.0f + expf(-v));
}
__device__ __forceinline__ unsigned short f2bf_rne(float f) {
    unsigned u = __float_as_uint(f);
    u += 0x7FFFu + ((u >> 16) & 1u);
    return (unsigned short)(u >> 16);
}
__device__ __forceinline__ float bf2f(unsigned short h) {
    return __uint_as_float((unsigned)h << 16);
}

// ---------------------------------------------------------------------------
// Persistent bidirectional LSTM, MFMA bf16x2 (hi+lo), W resident in VGPRs.
// Grid 256 x 512 (1 block/CU, 98.5 KB LDS). bid<128: h-role; else x-role.
// CU owns 64 gate-rows (4 gates x 16 units, units ub*16..+15), 64 m, K=1024.
// Waves: rt = wid&3 (16-row tile), kh = wid>>2 (512-k half).
// W-frags: whi/wlo[16] bf16x8 (128 VGPR), loaded+split once.
//   frag(kt): W[rt*16 + (lane&15)][kh*512 + kt*32 + (lane>>4)*8 + j]
// A staged per 128-k chunk: bf16 hi/lo panels [64 m][128 k] in LDS,
// 16B-slot XOR swizzle (slot ^= m&7), double-buffered, 1 barrier/chunk.
// gates = 3 mfma per (mt, kt): Whi*Ahi + Whi*Alo + Wlo*Ahi (f32 accum).
// k-half partials combined once via LDS pg. c-state in regs; gx ring in ws;
// proven 2-level grid barrier per round.
// ---------------------------------------------------------------------------
__global__ __launch_bounds__(512, 2) void lstm_mfma(
    const float* __restrict__ x,
    const float* __restrict__ h0f, const float* __restrict__ c0f,
    const float* __restrict__ h0b, const float* __restrict__ c0b,
    const float* __restrict__ wihf, const float* __restrict__ whhf,
    const float* __restrict__ bihf, const float* __restrict__ bhhf,
    const float* __restrict__ wihb, const float* __restrict__ whhb,
    const float* __restrict__ bihb, const float* __restrict__ bhhb,
    float* __restrict__ out, float* __restrict__ gx, int* __restrict__ bar)
{
    __shared__ short AhL[2][8192];   // [buf][64 m][128 k] bf16-hi, swizzled
    __shared__ short AlL[2][8192];   // bf16-lo
    __shared__ float pg[64 * 65];    // k-half-1 partial C
    __shared__ float Lg[64 * 65];    // combined gates (h-role)

    const int tid = threadIdx.x;
    const int bid = blockIdx.x;
    const bool hrole = (bid < 128);
    const int rid = bid & 127;
    const int dir = rid >> 6;
    const int ub  = rid & 63;
    const int wid = tid >> 6;
    const int rt  = wid & 3;         // row-tile: local rows rt*16..+15
    const int kh  = wid >> 2;        // k-half
    const int lane = tid & 63;
    const int l15 = lane & 15;
    const int kg  = lane >> 4;       // k-group 0..3 in frag

    const float* W = hrole ? (dir ? whhb : whhf) : (dir ? wihb : wihf);

    // ---- W fragments: load f32, split to bf16 hi/lo, resident ----
    bf16x8 whi[16], wlo[16];
    {
        const int rloc = rt * 16 + l15;
        const int grow = (rloc >> 4) * H_DIM + ub * 16 + (rloc & 15);
        const float* wbase = W + (size_t)grow * 1024 + kh * 512 + kg * 8;
#pragma unroll
        for (int kt = 0; kt < 16; ++kt) {
            const float4 w0 = *reinterpret_cast<const float4*>(wbase + kt * 32);
            const float4 w1 = *reinterpret_cast<const float4*>(wbase + kt * 32 + 4);
            const float wf[8] = {w0.x, w0.y, w0.z, w0.w, w1.x, w1.y, w1.z, w1.w};
            bf16x8 hv, lv;
#pragma unroll
            for (int j = 0; j < 8; ++j) {
                const unsigned short hb = f2bf_rne(wf[j]);
                const unsigned short lb = f2bf_rne(wf[j] - bf2f(hb));
                hv[j] = (short)hb;
                lv[j] = (short)lb;
            }
            whi[kt] = hv;
            wlo[kt] = lv;
        }
    }

    // x-role: bias per acc row (depends on v only)
    float bias_v[4] = {0.f, 0.f, 0.f, 0.f};
    if (!hrole) {
        const float* bi = dir ? bihb : bihf;
        const float* bh = dir ? bhhb : bhhf;
#pragma unroll
        for (int v = 0; v < 4; ++v) {
            const int rl = rt * 16 + kg * 4 + v;
            const int gr = (rl >> 4) * H_DIM + ub * 16 + (rl & 15);
            bias_v[v] = bi[gr] + bh[gr];
        }
    }

    // h-role: persistent c-state, cells 2*tid, 2*tid+1 -> (m = cell>>4, u = cell&15)
    float creg[2] = {0.f, 0.f};
    if (hrole) {
        const float* ci = dir ? c0b : c0f;
#pragma unroll
        for (int e = 0; e < 2; ++e) {
            const int cell = 2 * tid + e;
            creg[e] = ci[(size_t)(cell >> 4) * H_DIM + ub * 16 + (cell & 15)];
        }
    }

    for (int r = 0; r <= T_DIM; ++r) {
        const int s = hrole ? (r - 1) : r;
        const bool active = (s >= 0) && (s < T_DIM);

        if (active) {
            const int tt = dir ? (T_DIM - 1 - s) : s;
            const float* A;
            int sA;
            if (hrole) {
                if (s == 0) { A = dir ? h0b : h0f; sA = H_DIM; }
                else {
                    const int tp = dir ? (tt + 1) : (tt - 1);
                    A = out + (size_t)tp * B_DIM * 2 * H_DIM + dir * H_DIM;
                    sA = 2 * H_DIM;
                }
            } else {
                A = x + (size_t)tt * B_DIM * I_DIM;
                sA = I_DIM;
            }

            f32x4 acc[4];
#pragma unroll
            for (int mt = 0; mt < 4; ++mt) acc[mt] = (f32x4){0.f, 0.f, 0.f, 0.f};

            float4 ld4[4];
            auto stage_load = [&](int c) {
#pragma unroll
                for (int p = 0; p < 4; ++p) {
                    const int sl = p * 512 + tid;
                    const int m = sl >> 5, q = sl & 31;
                    ld4[p] = *reinterpret_cast<const float4*>(
                        A + (size_t)m * sA + c * 128 + q * 4);
                }
            };
            auto stage_write = [&](int buf) {
#pragma unroll
                for (int p = 0; p < 4; ++p) {
                    const int sl = p * 512 + tid;
                    const int m = sl >> 5, q = sl & 31;
                    const int off = m * 128 + (((q >> 1) ^ (m & 7)) << 3)
                                    + (q & 1) * 4;
                    const float fv[4] = {ld4[p].x, ld4[p].y, ld4[p].z, ld4[p].w};
                    short hv[4], lv[4];
#pragma unroll
                    for (int j = 0; j < 4; ++j) {
                        const unsigned short hb = f2bf_rne(fv[j]);
                        hv[j] = (short)hb;
                        lv[j] = (short)f2bf_rne(fv[j] - bf2f(hb));
                    }
                    *reinterpret_cast<short4*>(&AhL[buf][off]) =
                        make_short4(hv[0], hv[1], hv[2], hv[3]);
                    *reinterpret_cast<short4*>(&AlL[buf][off]) =
                        make_short4(lv[0], lv[1], lv[2], lv[3]);
                }
            };

            stage_load(0);
#pragma unroll
            for (int c = 0; c < 8; ++c) {
                stage_write(c & 1);
                if (c < 7) stage_load(c + 1);
                __syncthreads();
                if (kh == (c >> 2)) {
#pragma unroll
                    for (int ktl = 0; ktl < 4; ++ktl) {
                        const int kt = (c & 3) * 4 + ktl;   // static
#pragma unroll
                        for (int mt = 0; mt < 4; ++mt) {
                            const int row = mt * 16 + l15;
                            const int off = row * 128
                                + ((((ktl * 4 + kg) ^ (row & 7))) << 3);
                            const bf16x8 ah =
                                *reinterpret_cast<const bf16x8*>(&AhL[c & 1][off]);
                            const bf16x8 al =
                                *reinterpret_cast<const bf16x8*>(&AlL[c & 1][off]);
                            acc[mt] = __builtin_amdgcn_mfma_f32_16x16x32_bf16(
                                whi[kt], ah, acc[mt], 0, 0, 0);
                            acc[mt] = __builtin_amdgcn_mfma_f32_16x16x32_bf16(
                                whi[kt], al, acc[mt], 0, 0, 0);
                            acc[mt] = __builtin_amdgcn_mfma_f32_16x16x32_bf16(
                                wlo[kt], ah, acc[mt], 0, 0, 0);
                        }
                    }
                }
            }

            // ---- combine k-halves ----
            __syncthreads();
            if (kh == 1) {
#pragma unroll
                for (int mt = 0; mt < 4; ++mt)
#pragma unroll
                    for (int v = 0; v < 4; ++v)
                        pg[(rt * 16 + kg * 4 + v) * 65 + mt * 16 + l15] =
                            acc[mt][v];
            }
            __syncthreads();
            if (kh == 0) {
                if (hrole) {
                    const float* grd = gx
                        + (((size_t)(s & 1) * 2 + dir) * 64 + ub) * 4096;
#pragma unroll
                    for (int mt = 0; mt < 4; ++mt)
#pragma unroll
                        for (int v = 0; v < 4; ++v) {
                            const int rl = rt * 16 + kg * 4 + v;
                            const float sum = acc[mt][v]
                                + pg[rl * 65 + mt * 16 + l15]
                                + grd[rl * 64 + mt * 16 + l15];
                            Lg[rl * 65 + mt * 16 + l15] = sum;
                        }
                } else {
                    float* gw = gx
                        + (((size_t)(s & 1) * 2 + dir) * 64 + ub) * 4096;
#pragma unroll
                    for (int mt = 0; mt < 4; ++mt)
#pragma unroll
                        for (int v = 0; v < 4; ++v) {
                            const int rl = rt * 16 + kg * 4 + v;
                            gw[rl * 64 + mt * 16 + l15] = acc[mt][v]
                                + pg[rl * 65 + mt * 16 + l15] + bias_v[v];
                        }
                }
            }

            if (hrole) {
                __syncthreads();
                // ---- cell update: 2 adjacent cells/thread ----
                float hv2[2];
#pragma unroll
                for (int e = 0; e < 2; ++e) {
                    const int cell = 2 * tid + e;
                    const int m = cell >> 4, u = cell & 15;
                    const float ig = Lg[(0 * 16 + u) * 65 + m];
                    const float fg = Lg[(1 * 16 + u) * 65 + m];
                    const float gg = Lg[(2 * 16 + u) * 65 + m];
                    const float og = Lg[(3 * 16 + u) * 65 + m];
                    const float cn = sigmoidf_(fg) * creg[e]
                                   + sigmoidf_(ig) * tanhf(gg);
                    hv2[e] = sigmoidf_(og) * tanhf(cn);
                    creg[e] = cn;
                }
                const int m = (2 * tid) >> 4, u = (2 * tid) & 15;
                *reinterpret_cast<float2*>(
                    out + (size_t)tt * B_DIM * 2 * H_DIM
                    + (size_t)m * 2 * H_DIM + dir * H_DIM + ub * 16 + u) =
                    make_float2(hv2[0], hv2[1]);
                if (s == T_DIM - 1) {
                    float* hs = out + (dir ? OUT_HTB : OUT_HTF);
                    float* cs = out + (dir ? OUT_CTB : OUT_CTF);
                    *reinterpret_cast<float2*>(
                        hs + (size_t)m * H_DIM + ub * 16 + u) =
                        make_float2(hv2[0], hv2[1]);
                    *reinterpret_cast<float2*>(
                        cs + (size_t)m * H_DIM + ub * 16 + u) =
                        make_float2(creg[0], creg[1]);
                }
            }
        }

        // ---- grid barrier, generation r+1 ----
        if (r < T_DIM) {
            __threadfence();
            __syncthreads();
            if (tid == 0) {
                const int grp = bid >> 5;
                __hip_atomic_fetch_add(&bar[grp], 1, __ATOMIC_RELEASE,
                                       __HIP_MEMORY_SCOPE_AGENT);
                if ((bid & 31) == 0) {
                    while (__hip_atomic_load(&bar[grp], __ATOMIC_ACQUIRE,
                                             __HIP_MEMORY_SCOPE_AGENT)
                           < 32 * (r + 1))
                        __builtin_amdgcn_s_sleep(2);
                    __hip_atomic_fetch_add(&bar[8], 1, __ATOMIC_RELEASE,
                                           __HIP_MEMORY_SCOPE_AGENT);
                }
                while (__hip_atomic_load(&bar[8], __ATOMIC_ACQUIRE,
                                         __HIP_MEMORY_SCOPE_AGENT)
                       < 8 * (r + 1))
                    __builtin_amdgcn_s_sleep(2);
            }
            __syncthreads();
            __threadfence();
        }
    }
}

extern "C" void kernel_launch(void* const* d_in, const int* in_sizes, int n_in,
                              void* d_out, int out_size, void* d_ws, size_t ws_size,
                              hipStream_t stream)
{
    const float* x    = (const float*)d_in[0];
    const float* h0f  = (const float*)d_in[1];
    const float* c0f  = (const float*)d_in[2];
    const float* h0b  = (const float*)d_in[3];
    const float* c0b  = (const float*)d_in[4];
    const float* wihf = (const float*)d_in[5];
    const float* whhf = (const float*)d_in[6];
    const float* bihf = (const float*)d_in[7];
    const float* bhhf = (const float*)d_in[8];
    const float* wihb = (const float*)d_in[9];
    const float* whhb = (const float*)d_in[10];
    const float* bihb = (const float*)d_in[11];
    const float* bhhb = (const float*)d_in[12];
    float* out = (float*)d_out;

    // ws: [0,256) barrier counters, [256, 256+4MB) gx ring (2 slots x 2MB)
    hipMemsetAsync(d_ws, 0, 256, stream);
    float* gx = (float*)((char*)d_ws + 256);
    lstm_mfma<<<dim3(256), dim3(512), 0, stream>>>(
        x, h0f, c0f, h0b, c0b,
        wihf, whhf, bihf, bhhf,
        wihb, whhb, bihb, bhhb,
        out, gx, (int*)d_ws);
}